// Round 22
// baseline (881.775 us; speedup 1.0000x reference)
//
#include <hip/hip_runtime.h>
#include <math.h>

// AddrNet eval forward: B=524288, D_MODEL=128, HID=16, N_BINS=256, DEPTH=8.
// Round 22: two-pass MFMA screen (R21 base, tracker restructured):
//  Pass 1: per-row MAX only (0.75 VALU/value via max trees).
//  Pass 2: MFMAs RECOMPUTED (matrix pipe 9% utilized -> free; asm memory
//    clobber between passes blocks CSE so accumulators are never kept live),
//    candidate scan v >= mx-EPS2 at 5 ops/value tracking lowest+highest
//    candidate bin.
//  Resolution: imin==imax -> unique candidate -> certified argmax (same
//    R15-validated bound, 3.5x margin); else full exact no-FMA argmax
//    (first-index ties, R4 semantics). Duel path deleted (subsumed).
//  Output bins buffered in regs, stored once as 2x int4 (R19-proven).
// h-trajectory (input, embed, MLP, np-Cephes exp, mul-silu): bit-exact
// no-FMA R4 contract, unchanged.

constexpr int BATCH  = 524288;
constexpr int DM     = 128;
constexpr int H      = 16;
constexpr int NB     = 256;
constexpr int DEPTHN = 8;

constexpr int BLOCK = 512;
constexpr int NWAVE = BLOCK / 64;
constexpr int STG   = 17;          // odd stride: conflict-free scalar stage

typedef float v2f    __attribute__((ext_vector_type(2)));
typedef float f32x4  __attribute__((ext_vector_type(4)));
typedef int   i32x4  __attribute__((ext_vector_type(4)));
typedef short bf16x8 __attribute__((ext_vector_type(8)));

__device__ __forceinline__ unsigned bf16_rne(float f) {
    unsigned u = __builtin_bit_cast(unsigned, f);
    return (u + 0x7fffu + ((u >> 16) & 1u)) >> 16;
}
__device__ __forceinline__ float bf16_to_f(unsigned b) {
    return __builtin_bit_cast(float, b << 16);
}

__device__ __forceinline__ float np_expf(float x) {
    // numpy SIMD f32 exp replica (Cephes). Verified R4 contract — do not touch.
    const float LOG2E = 1.442695040888963407f;
    const float C1    = 0.693359375f;
    const float C2    = -2.12194440e-4f;
    float q = rintf(x * LOG2E);
    float r = __builtin_fmaf(q, -C1, x);
    r = __builtin_fmaf(q, -C2, r);
    float p = 1.9875691500E-4f;
    p = __builtin_fmaf(p, r, 1.3981999507E-3f);
    p = __builtin_fmaf(p, r, 8.3334519073E-3f);
    p = __builtin_fmaf(p, r, 4.1665795894E-2f);
    p = __builtin_fmaf(p, r, 1.6666665459E-1f);
    p = __builtin_fmaf(p, r, 5.0000001201E-1f);
    p = __builtin_fmaf(p, r * r, r);
    p = p + 1.0f;
    if (x > 88.72283935546875f)      return INFINITY;
    if (x < -103.97208404541015625f) return 0.0f;
    return ldexpf(p, (int)q);
}

// ---- prep: exact-path weight layouts in d_ws (same as R14-R21).
//   ws[p*32 + k*2 + hh] = W_out[k][2p+hh]   p in [0,128)
//   ws[4096 + i*16 + k] = W_mlp[k][i]
__global__ void addrnet_prep_kernel(const float* __restrict__ W_out,
                                    const float* __restrict__ W_mlp,
                                    float* __restrict__ ws) {
    int t = threadIdx.x;
    for (int i = t; i < NB * H; i += 256) {
        int p = i >> 5, r = i & 31;
        int k = r >> 1, hh = r & 1;
        ws[i] = W_out[k * NB + (2 * p + hh)];
    }
    {
        int ii = t >> 4, k = t & 15;
        ws[NB * H + ii * H + k] = W_mlp[k * H + ii];
    }
}

__global__ __launch_bounds__(BLOCK, 3) void addrnet_r22_kernel(
    const float* __restrict__ x,      // [B,128]
    const float* __restrict__ W_in,   // [128,16]
    const float* __restrict__ b_in,   // [16]
    const float* __restrict__ embed,  // [256,16]
    const float* __restrict__ b_mlp,  // [16]
    const float* __restrict__ b_out,  // [256]
    const float* __restrict__ W_out,  // [16,256] (A-frag build)
    const float* __restrict__ ws,     // exact-path layouts
    int* __restrict__ out)            // [B,8] int32
{
#pragma clang fp contract(off)
    __shared__ __align__(16) int   sA[16][64][4];           // 16 KB (x8 waves)
    __shared__ __align__(16) int   sStage[NWAVE][64 * STG]; // 34816 B
    __shared__ __align__(16) float sBias[NB];               //  1 KB
    // total 52224 B -> 3 blocks/CU -> 24 waves/CU

    const int tid = threadIdx.x;
    const int ln  = tid & 63;
    const int wid = tid >> 6;

    // ---- build A-fragments (variant0), verified in R15-R21 ----
    for (int slot = tid; slot < 16 * 64; slot += BLOCK) {
        int bt = slot >> 6, l = slot & 63;
        int m  = 16 * bt + (l & 15);
        int k0 = (l >> 4) * 8;
        for (int j = 0; j < 4; ++j) {
            unsigned e2[2];
            for (int e = 0; e < 2; ++e) {
                int k  = k0 + 2 * j + e;
                int kk = k & 15;
                float w = W_out[kk * NB + m];
                unsigned whi = bf16_rne(w);
                unsigned wlo = bf16_rne(w - bf16_to_f(whi));
                e2[e] = (k < 16) ? whi : wlo;
            }
            sA[bt][l][j] = (int)(e2[0] | (e2[1] << 16));
        }
    }
    if (tid < NB) sBias[tid] = b_out[tid];
    __syncthreads();

    const float* WM = ws + NB * H;                       // WmlpT[i][k]
    const v2f*   WP = reinterpret_cast<const v2f*>(ws);  // exact pair layout

    const int row = blockIdx.x * BLOCK + tid;

    // ---- h = x @ W_in + b_in : EXACT no-FMA, k ascending, bias after ----
    float h[H];
#pragma unroll
    for (int j = 0; j < H; ++j) h[j] = 0.0f;
    const float4* xr = reinterpret_cast<const float4*>(x + (size_t)row * DM);
    for (int k4 = 0; k4 < DM / 4; ++k4) {
        float4 v = xr[k4];
        const float* w0 = &W_in[(k4 * 4 + 0) * H];
        const float* w1 = &W_in[(k4 * 4 + 1) * H];
        const float* w2 = &W_in[(k4 * 4 + 2) * H];
        const float* w3 = &W_in[(k4 * 4 + 3) * H];
#pragma unroll
        for (int j = 0; j < H; ++j) {
            float a = h[j];
            a = a + v.x * w0[j];
            a = a + v.y * w1[j];
            a = a + v.z * w2[j];
            a = a + v.w * w3[j];
            h[j] = a;
        }
    }
#pragma unroll
    for (int j = 0; j < H; ++j) h[j] = h[j] + b_in[j];

    int* stme = &sStage[wid][ln * STG];
    const int binbase = (ln >> 4) * 4;
    int bins_[DEPTHN];

    for (int d = 0; d < DEPTHN; ++d) {
        // hmax (tree) for this lane's OWN row (row == ln within wave)
        float m01 = fmaxf(fabsf(h[0]), fabsf(h[1]));
        float m23 = fmaxf(fabsf(h[2]), fabsf(h[3]));
        float m45 = fmaxf(fabsf(h[4]), fabsf(h[5]));
        float m67 = fmaxf(fabsf(h[6]), fabsf(h[7]));
        float m89 = fmaxf(fabsf(h[8]), fabsf(h[9]));
        float mab = fmaxf(fabsf(h[10]), fabsf(h[11]));
        float mcd = fmaxf(fabsf(h[12]), fabsf(h[13]));
        float mef = fmaxf(fabsf(h[14]), fabsf(h[15]));
        float hmax = fmaxf(fmaxf(fmaxf(m01, m23), fmaxf(m45, m67)),
                           fmaxf(fmaxf(m89, mab), fmaxf(mcd, mef)));

        // ---- bf16 2-term split; dwords [hi pairs(8) | lo pairs(8)] ----
        int dw[16];
#pragma unroll
        for (int i = 0; i < 8; ++i) {
            unsigned a  = bf16_rne(h[2 * i]);
            unsigned b  = bf16_rne(h[2 * i + 1]);
            unsigned la = bf16_rne(h[2 * i]     - bf16_to_f(a));
            unsigned lb = bf16_rne(h[2 * i + 1] - bf16_to_f(b));
            dw[i]     = (int)(a  | (b  << 16));
            dw[8 + i] = (int)(la | (lb << 16));
        }
#pragma unroll
        for (int i = 0; i < 16; ++i) stme[i] = dw[i];   // scalar, stride-17 safe

        // ---- B-frags (h): rowgroup g, lane ln: row (ln&15)+16g, kgrp ln>>4 ----
        bf16x8 bfr[4];
#pragma unroll
        for (int g = 0; g < 4; ++g) {
            const int* p = &sStage[wid][((ln & 15) + 16 * g) * STG + (ln >> 4) * 4];
            i32x4 v = {p[0], p[1], p[2], p[3]};
            bfr[g] = __builtin_bit_cast(bf16x8, v);
        }

        // ======== PASS 1: per-rowgroup running MAX only ========
        float mxg[4] = {-INFINITY, -INFINITY, -INFINITY, -INFINITY};
        for (int bt = 0; bt < 16; ++bt) {
            i32x4 a0i = *reinterpret_cast<const i32x4*>(&sA[bt][ln][0]);
            i32x4 a1i = *reinterpret_cast<const i32x4*>(&sA[bt][ln ^ 32][0]);
            bf16x8 a0 = __builtin_bit_cast(bf16x8, a0i);
            bf16x8 a1 = __builtin_bit_cast(bf16x8, a1i);
            f32x4 bias4 = *reinterpret_cast<const f32x4*>(&sBias[16 * bt + binbase]);
#pragma unroll
            for (int g = 0; g < 4; ++g) {
                f32x4 acc = bias4;
                acc = __builtin_amdgcn_mfma_f32_16x16x32_bf16(a0, bfr[g], acc, 0, 0, 0);
                acc = __builtin_amdgcn_mfma_f32_16x16x32_bf16(a1, bfr[g], acc, 0, 0, 0);
                float q01 = fmaxf(acc[0], acc[1]);
                float q23 = fmaxf(acc[2], acc[3]);
                mxg[g] = fmaxf(mxg[g], fmaxf(q01, q23));
            }
        }
        // merge max across the 4 holder lanes (xor16, xor32)
#pragma unroll
        for (int g = 0; g < 4; ++g) {
            float m = mxg[g];
            m = fmaxf(m, __shfl_xor(m, 16));
            m = fmaxf(m, __shfl_xor(m, 32));
            mxg[g] = m;
        }
        // per-g threshold: row of tuple g is (ln&15)+16g; its hmax via shfl
        float thr[4];
#pragma unroll
        for (int g = 0; g < 4; ++g) {
            float hsrc = __shfl(hmax, (ln & 15) + 16 * g);
            thr[g] = mxg[g] - (6e-4f * hsrc + 1e-5f);
        }

        // block CSE of pass-1 MFMAs (force fresh LDS loads + fresh MFMAs)
        asm volatile("" ::: "memory");

        // ======== PASS 2: candidate scan (v >= thr), track min/max bin ====
        int imn[4] = {1023, 1023, 1023, 1023};
        int imx[4] = {-1, -1, -1, -1};
        for (int bt = 0; bt < 16; ++bt) {
            i32x4 a0i = *reinterpret_cast<const i32x4*>(&sA[bt][ln][0]);
            i32x4 a1i = *reinterpret_cast<const i32x4*>(&sA[bt][ln ^ 32][0]);
            bf16x8 a0 = __builtin_bit_cast(bf16x8, a0i);
            bf16x8 a1 = __builtin_bit_cast(bf16x8, a1i);
            f32x4 bias4 = *reinterpret_cast<const f32x4*>(&sBias[16 * bt + binbase]);
            int bin0 = 16 * bt + binbase;
#pragma unroll
            for (int g = 0; g < 4; ++g) {
                f32x4 acc = bias4;
                acc = __builtin_amdgcn_mfma_f32_16x16x32_bf16(a0, bfr[g], acc, 0, 0, 0);
                acc = __builtin_amdgcn_mfma_f32_16x16x32_bf16(a1, bfr[g], acc, 0, 0, 0);
#pragma unroll
                for (int r = 0; r < 4; ++r) {
                    bool hit = acc[r] >= thr[g];
                    int b = bin0 + r;
                    int clo = hit ? b : 1023;
                    int chi = hit ? b : -1;
                    imn[g] = clo < imn[g] ? clo : imn[g];
                    imx[g] = chi > imx[g] ? chi : imx[g];
                }
            }
        }
        // merge candidate min/max across holder lanes
#pragma unroll
        for (int g = 0; g < 4; ++g) {
            int a = imn[g];
            {
                int p = __shfl_xor(a, 16); a = p < a ? p : a;
                p = __shfl_xor(a, 32);     a = p < a ? p : a;
            }
            imn[g] = a;
            int b = imx[g];
            {
                int p = __shfl_xor(b, 16); b = p > b ? p : b;
                p = __shfl_xor(b, 32);     b = p > b ? p : b;
            }
            imx[g] = b;
        }

        // own tuple select (runtime g -> cndmask chain, no dynamic indexing)
        const int g_own = ln >> 4;
        int kmin = g_own == 0 ? imn[0] : g_own == 1 ? imn[1]
                 : g_own == 2 ? imn[2] : imn[3];
        int kmax = g_own == 0 ? imx[0] : g_own == 1 ? imx[1]
                 : g_own == 2 ? imx[2] : imx[3];

        // ---- certified resolution: unique candidate -> take; else exact ----
        int bi;
        if (kmin == kmax) {
            bi = kmin;
        } else {
            // full exact no-FMA argmax (rare; first-index ties, R4 semantics)
            float bb2 = -INFINITY;
            int bj = 0;
            for (int p = 0; p < NB / 2; ++p) {
                const v2f* wr = &WP[p * H];
                float a0 = 0.0f, a1 = 0.0f;
#pragma unroll
                for (int k = 0; k < H; ++k) {
                    v2f w = wr[k];
                    a0 = a0 + h[k] * w.x;
                    a1 = a1 + h[k] * w.y;
                }
                a0 = a0 + b_out[2 * p];
                a1 = a1 + b_out[2 * p + 1];
                if (a0 > bb2) { bb2 = a0; bj = 2 * p; }
                if (a1 > bb2) { bb2 = a1; bj = 2 * p + 1; }
            }
            bi = bj;
        }
        bins_[d] = bi;

        // ---- h = h + embed[bi] : EXACT (global gather, cached) ----
        {
            const float4* e = reinterpret_cast<const float4*>(embed + bi * H);
#pragma unroll
            for (int q4 = 0; q4 < 4; ++q4) {
                float4 ev = e[q4];
                h[q4 * 4 + 0] = h[q4 * 4 + 0] + ev.x;
                h[q4 * 4 + 1] = h[q4 * 4 + 1] + ev.y;
                h[q4 * 4 + 2] = h[q4 * 4 + 2] + ev.z;
                h[q4 * 4 + 3] = h[q4 * 4 + 3] + ev.w;
            }
        }

        // ---- z = h @ W_mlp + b_mlp ; silu : EXACT no-FMA + np-exp ----
        float hn[H];
#pragma unroll
        for (int i = 0; i < H; ++i) {
            const float* wr = &WM[i * H];
            float acc = 0.0f;
#pragma unroll
            for (int k = 0; k < H; ++k) acc = acc + h[k] * wr[k];
            acc = acc + b_mlp[i];
            float e = np_expf(-acc);
            float s = 1.0f / (1.0f + e);
            hn[i] = acc * s;
        }
#pragma unroll
        for (int i = 0; i < H; ++i) h[i] = hn[i];
    }

    // ---- write all bins once: 2x int4, coalesced ----
    int* o = out + (size_t)row * DEPTHN;
    *reinterpret_cast<int4*>(o)     = make_int4(bins_[0], bins_[1], bins_[2], bins_[3]);
    *reinterpret_cast<int4*>(o + 4) = make_int4(bins_[4], bins_[5], bins_[6], bins_[7]);
}

extern "C" void kernel_launch(void* const* d_in, const int* in_sizes, int n_in,
                              void* d_out, int out_size, void* d_ws, size_t ws_size,
                              hipStream_t stream) {
    const float* x     = (const float*)d_in[0];
    const float* W_in  = (const float*)d_in[1];
    const float* b_in  = (const float*)d_in[2];
    const float* embed = (const float*)d_in[3];
    const float* W_mlp = (const float*)d_in[4];
    const float* b_mlp = (const float*)d_in[5];
    const float* W_out = (const float*)d_in[6];
    const float* b_out = (const float*)d_in[7];
    int* out  = (int*)d_out;
    float* ws = (float*)d_ws;          // needs (4096+256)*4 = 17.4 KB

    addrnet_prep_kernel<<<1, 256, 0, stream>>>(W_out, W_mlp, ws);

    dim3 grid(BATCH / BLOCK);          // 1024 blocks, 8192 waves
    dim3 block(BLOCK);
    addrnet_r22_kernel<<<grid, block, 0, stream>>>(x, W_in, b_in, embed,
                                                   b_mlp, b_out, W_out, ws, out);
}

// Round 23
// 615.630 us; speedup vs baseline: 1.4323x; 1.4323x over previous
//
#include <hip/hip_runtime.h>
#include <math.h>

// AddrNet eval forward: B=524288, D_MODEL=128, HID=16, N_BINS=256, DEPTH=8.
// FINAL (R21 restore, measured 616.7us, absmax 0): MFMA bf16-2-term screened
// argmax with certified exact resolution.
//  - h-trajectory (input layer, embed add, MLP, np-Cephes exp, mul-silu):
//    bit-exact no-FMA float32 replication of the numpy reference (R4 contract:
//    separate mul/add roundings, k-ascending sums, bias-after).
//  - logits: bf16 2-term split (h=hi+lo, W=whi+wlo), 2x mfma_f32_16x16x32_bf16
//    per tile with the ln^32 variant trick; bias in C-init.
//  - top-3+index tracker (med3/min form) + 2-shfl merge; EPS2=6e-4*hmax+1e-5
//    certification: unique -> take; 2-within -> exact no-FMA duel; 3-within ->
//    full exact no-FMA argmax (first-index ties, numpy semantics).
//  - BLOCK=512 shares the 16KB W-frag LDS across 8 waves; 52224B LDS,
//    (512,4) -> 64-VGPR cap, 56 used, no spill.
// Measured-null/negative and rejected: pk-f32 (half-rate), fmaf scalar screen,
// stuffed tracker (dep-chain bound), two-pass recompute, STG=15 (corrupt).

constexpr int BATCH  = 524288;
constexpr int DM     = 128;
constexpr int H      = 16;
constexpr int NB     = 256;
constexpr int DEPTHN = 8;

constexpr int BLOCK = 512;
constexpr int NWAVE = BLOCK / 64;
constexpr int STG   = 17;          // odd stride: conflict-free scalar stage

typedef float v2f    __attribute__((ext_vector_type(2)));
typedef float f32x4  __attribute__((ext_vector_type(4)));
typedef int   i32x4  __attribute__((ext_vector_type(4)));
typedef short bf16x8 __attribute__((ext_vector_type(8)));

__device__ __forceinline__ unsigned bf16_rne(float f) {
    unsigned u = __builtin_bit_cast(unsigned, f);
    return (u + 0x7fffu + ((u >> 16) & 1u)) >> 16;
}
__device__ __forceinline__ float bf16_to_f(unsigned b) {
    return __builtin_bit_cast(float, b << 16);
}

__device__ __forceinline__ float np_expf(float x) {
    // numpy SIMD f32 exp replica (Cephes). Verified R4 contract — do not touch.
    const float LOG2E = 1.442695040888963407f;
    const float C1    = 0.693359375f;
    const float C2    = -2.12194440e-4f;
    float q = rintf(x * LOG2E);
    float r = __builtin_fmaf(q, -C1, x);
    r = __builtin_fmaf(q, -C2, r);
    float p = 1.9875691500E-4f;
    p = __builtin_fmaf(p, r, 1.3981999507E-3f);
    p = __builtin_fmaf(p, r, 8.3334519073E-3f);
    p = __builtin_fmaf(p, r, 4.1665795894E-2f);
    p = __builtin_fmaf(p, r, 1.6666665459E-1f);
    p = __builtin_fmaf(p, r, 5.0000001201E-1f);
    p = __builtin_fmaf(p, r * r, r);
    p = p + 1.0f;
    if (x > 88.72283935546875f)      return INFINITY;
    if (x < -103.97208404541015625f) return 0.0f;
    return ldexpf(p, (int)q);
}

// ---- prep: exact-path weight layouts in d_ws.
//   ws[p*32 + k*2 + hh] = W_out[k][2p+hh]   p in [0,128)
//   ws[4096 + i*16 + k] = W_mlp[k][i]
__global__ void addrnet_prep_kernel(const float* __restrict__ W_out,
                                    const float* __restrict__ W_mlp,
                                    float* __restrict__ ws) {
    int t = threadIdx.x;
    for (int i = t; i < NB * H; i += 256) {
        int p = i >> 5, r = i & 31;
        int k = r >> 1, hh = r & 1;
        ws[i] = W_out[k * NB + (2 * p + hh)];
    }
    {
        int ii = t >> 4, k = t & 15;
        ws[NB * H + ii * H + k] = W_mlp[k * H + ii];
    }
}

__global__ __launch_bounds__(BLOCK, 4) void addrnet_r21_kernel(
    const float* __restrict__ x,      // [B,128]
    const float* __restrict__ W_in,   // [128,16]
    const float* __restrict__ b_in,   // [16]
    const float* __restrict__ embed,  // [256,16]
    const float* __restrict__ b_mlp,  // [16]
    const float* __restrict__ b_out,  // [256]
    const float* __restrict__ W_out,  // [16,256] (A-frag build)
    const float* __restrict__ ws,     // exact-path layouts
    int* __restrict__ out)            // [B,8] int32
{
#pragma clang fp contract(off)
    __shared__ __align__(16) int   sA[16][64][4];           // 16 KB (shared x8 waves)
    __shared__ __align__(16) int   sStage[NWAVE][64 * STG]; // 34816 B
    __shared__ __align__(16) float sBias[NB];               //  1 KB
    // total 52224 B -> 3 blocks/CU -> 24 waves/CU

    const int tid = threadIdx.x;
    const int ln  = tid & 63;
    const int wid = tid >> 6;

    // ---- build A-fragments (variant0), verified in R15-R21 ----
    for (int slot = tid; slot < 16 * 64; slot += BLOCK) {
        int bt = slot >> 6, l = slot & 63;
        int m  = 16 * bt + (l & 15);
        int k0 = (l >> 4) * 8;
        for (int j = 0; j < 4; ++j) {
            unsigned e2[2];
            for (int e = 0; e < 2; ++e) {
                int k  = k0 + 2 * j + e;
                int kk = k & 15;
                float w = W_out[kk * NB + m];
                unsigned whi = bf16_rne(w);
                unsigned wlo = bf16_rne(w - bf16_to_f(whi));
                e2[e] = (k < 16) ? whi : wlo;
            }
            sA[bt][l][j] = (int)(e2[0] | (e2[1] << 16));
        }
    }
    if (tid < NB) sBias[tid] = b_out[tid];
    __syncthreads();

    const float* WM = ws + NB * H;                       // WmlpT[i][k]
    const v2f*   WP = reinterpret_cast<const v2f*>(ws);  // exact pair layout

    const int row = blockIdx.x * BLOCK + tid;

    // ---- h = x @ W_in + b_in : EXACT no-FMA, k ascending, bias after ----
    float h[H];
#pragma unroll
    for (int j = 0; j < H; ++j) h[j] = 0.0f;
    const float4* xr = reinterpret_cast<const float4*>(x + (size_t)row * DM);
    for (int k4 = 0; k4 < DM / 4; ++k4) {
        float4 v = xr[k4];
        const float* w0 = &W_in[(k4 * 4 + 0) * H];
        const float* w1 = &W_in[(k4 * 4 + 1) * H];
        const float* w2 = &W_in[(k4 * 4 + 2) * H];
        const float* w3 = &W_in[(k4 * 4 + 3) * H];
#pragma unroll
        for (int j = 0; j < H; ++j) {
            float a = h[j];
            a = a + v.x * w0[j];
            a = a + v.y * w1[j];
            a = a + v.z * w2[j];
            a = a + v.w * w3[j];
            h[j] = a;
        }
    }
#pragma unroll
    for (int j = 0; j < H; ++j) h[j] = h[j] + b_in[j];

    int* o = out + (size_t)row * DEPTHN;
    int* stme = &sStage[wid][ln * STG];
    const int binbase = (ln >> 4) * 4;

    for (int d = 0; d < DEPTHN; ++d) {
        // hmax (tree)
        float m01 = fmaxf(fabsf(h[0]), fabsf(h[1]));
        float m23 = fmaxf(fabsf(h[2]), fabsf(h[3]));
        float m45 = fmaxf(fabsf(h[4]), fabsf(h[5]));
        float m67 = fmaxf(fabsf(h[6]), fabsf(h[7]));
        float m89 = fmaxf(fabsf(h[8]), fabsf(h[9]));
        float mab = fmaxf(fabsf(h[10]), fabsf(h[11]));
        float mcd = fmaxf(fabsf(h[12]), fabsf(h[13]));
        float mef = fmaxf(fabsf(h[14]), fabsf(h[15]));
        float hmax = fmaxf(fmaxf(fmaxf(m01, m23), fmaxf(m45, m67)),
                           fmaxf(fmaxf(m89, mab), fmaxf(mcd, mef)));
        const float EPS2 = 6e-4f * hmax + 1e-5f;

        // ---- bf16 2-term split; dwords [hi pairs(8) | lo pairs(8)] ----
        int dw[16];
#pragma unroll
        for (int i = 0; i < 8; ++i) {
            unsigned a  = bf16_rne(h[2 * i]);
            unsigned b  = bf16_rne(h[2 * i + 1]);
            unsigned la = bf16_rne(h[2 * i]     - bf16_to_f(a));
            unsigned lb = bf16_rne(h[2 * i + 1] - bf16_to_f(b));
            dw[i]     = (int)(a  | (b  << 16));
            dw[8 + i] = (int)(la | (lb << 16));
        }
#pragma unroll
        for (int i = 0; i < 16; ++i) stme[i] = dw[i];   // scalar, stride-17 safe

        // ---- B-frags (h): rowgroup g, lane ln: row (ln&15)+16g, kgrp ln>>4 ----
        bf16x8 bfr[4];
#pragma unroll
        for (int g = 0; g < 4; ++g) {
            const int* p = &sStage[wid][((ln & 15) + 16 * g) * STG + (ln >> 4) * 4];
            i32x4 v = {p[0], p[1], p[2], p[3]};
            bfr[g] = __builtin_bit_cast(bf16x8, v);
        }

        // running tuples per rowgroup
        float mx0 = -INFINITY, sec0 = -INFINITY, t30 = -INFINITY; int gb0 = 0, i20 = 0;
        float mx1 = -INFINITY, sec1 = -INFINITY, t31 = -INFINITY; int gb1 = 0, i21 = 0;
        float mx2 = -INFINITY, sec2 = -INFINITY, t32 = -INFINITY; int gb2 = 0, i22 = 0;
        float mx3 = -INFINITY, sec3 = -INFINITY, t33 = -INFINITY; int gb3 = 0, i23 = 0;

        // 9-op insert (R18-proven):
        //   t3' = max(t3, min(sec, v)); idx updates by cmp;
        //   sec' = med3(mx, sec, v);    mx' = max(mx, v)
#define INS(MX, GB, SEC, I2, T3, V, BIN)                                   \
        {                                                                  \
            float v_ = (V); int b_ = (BIN);                                \
            T3 = fmaxf(T3, fminf(SEC, v_));                                \
            bool c1 = v_ > MX;                                             \
            bool c2 = v_ > SEC;                                            \
            I2 = c1 ? GB : (c2 ? b_ : I2);                                 \
            GB = c1 ? b_ : GB;                                             \
            SEC = __builtin_amdgcn_fmed3f(MX, SEC, v_);                    \
            MX = fmaxf(MX, v_);                                            \
        }

        for (int bt = 0; bt < 16; ++bt) {
            i32x4 a0i = *reinterpret_cast<const i32x4*>(&sA[bt][ln][0]);
            i32x4 a1i = *reinterpret_cast<const i32x4*>(&sA[bt][ln ^ 32][0]);
            bf16x8 a0 = __builtin_bit_cast(bf16x8, a0i);
            bf16x8 a1 = __builtin_bit_cast(bf16x8, a1i);
            f32x4 bias4 = *reinterpret_cast<const f32x4*>(&sBias[16 * bt + binbase]);
            int bin0 = 16 * bt + binbase;
#pragma unroll
            for (int g = 0; g < 4; ++g) {
                f32x4 acc = bias4;
                acc = __builtin_amdgcn_mfma_f32_16x16x32_bf16(a0, bfr[g], acc, 0, 0, 0);
                acc = __builtin_amdgcn_mfma_f32_16x16x32_bf16(a1, bfr[g], acc, 0, 0, 0);
                if (g == 0) {
                    INS(mx0, gb0, sec0, i20, t30, acc[0], bin0 + 0);
                    INS(mx0, gb0, sec0, i20, t30, acc[1], bin0 + 1);
                    INS(mx0, gb0, sec0, i20, t30, acc[2], bin0 + 2);
                    INS(mx0, gb0, sec0, i20, t30, acc[3], bin0 + 3);
                } else if (g == 1) {
                    INS(mx1, gb1, sec1, i21, t31, acc[0], bin0 + 0);
                    INS(mx1, gb1, sec1, i21, t31, acc[1], bin0 + 1);
                    INS(mx1, gb1, sec1, i21, t31, acc[2], bin0 + 2);
                    INS(mx1, gb1, sec1, i21, t31, acc[3], bin0 + 3);
                } else if (g == 2) {
                    INS(mx2, gb2, sec2, i22, t32, acc[0], bin0 + 0);
                    INS(mx2, gb2, sec2, i22, t32, acc[1], bin0 + 1);
                    INS(mx2, gb2, sec2, i22, t32, acc[2], bin0 + 2);
                    INS(mx2, gb2, sec2, i22, t32, acc[3], bin0 + 3);
                } else {
                    INS(mx3, gb3, sec3, i23, t33, acc[0], bin0 + 0);
                    INS(mx3, gb3, sec3, i23, t33, acc[1], bin0 + 1);
                    INS(mx3, gb3, sec3, i23, t33, acc[2], bin0 + 2);
                    INS(mx3, gb3, sec3, i23, t33, acc[3], bin0 + 3);
                }
            }
        }
#undef INS

        // ---- merge 4 bin-holder lanes (xor 16, 32) per rowgroup; keep own ----
        float kmx = -INFINITY, ksec = -INFINITY, kt3 = -INFINITY;
        int kgb = 0, ki2 = 0;
#define MERGE_KEEP(MX, GB, SEC, I2, T3, G)                                 \
        {                                                                  \
            float mx_ = MX, sec_ = SEC, t3_ = T3; int gb_ = GB, i2_ = I2;  \
            _Pragma("unroll")                                              \
            for (int s = 16; s <= 32; s <<= 1) {                           \
                float pmx = __shfl_xor(mx_, s);                            \
                int   pgb = __shfl_xor(gb_, s);                            \
                float pse = __shfl_xor(sec_, s);                           \
                int   pi2 = __shfl_xor(i2_, s);                            \
                float pt3 = __shfl_xor(t3_, s);                            \
                bool t  = pmx > mx_;                                       \
                float nmx = t ? pmx : mx_;  int ngb = t ? pgb : gb_;       \
                float lmx = t ? mx_ : pmx;  int lgb = t ? gb_ : pgb;       \
                float wse = t ? pse : sec_; int wsi = t ? pi2 : i2_;       \
                bool u  = lmx > wse;                                       \
                float nse = u ? lmx : wse;  int ni2 = u ? lgb : wsi;       \
                float c3  = u ? wse : lmx;                                 \
                float lse = t ? sec_ : pse;                                \
                float nt3 = fmaxf(fmaxf(c3, lse), fmaxf(t3_, pt3));        \
                mx_ = nmx; gb_ = ngb; sec_ = nse; i2_ = ni2; t3_ = nt3;    \
            }                                                              \
            bool own = ((ln >> 4) == (G));                                 \
            kmx = own ? mx_ : kmx;   kgb = own ? gb_ : kgb;                \
            ksec = own ? sec_ : ksec; ki2 = own ? i2_ : ki2;               \
            kt3 = own ? t3_ : kt3;                                         \
        }
        MERGE_KEEP(mx0, gb0, sec0, i20, t30, 0)
        MERGE_KEEP(mx1, gb1, sec1, i21, t31, 1)
        MERGE_KEEP(mx2, gb2, sec2, i22, t32, 2)
        MERGE_KEEP(mx3, gb3, sec3, i23, t33, 3)
#undef MERGE_KEEP

        // ---- certified resolution ----
        int bi;
        if (kmx - kt3 <= EPS2) {
            // full exact no-FMA argmax (rare)
            float bb2 = -INFINITY;
            int bj = 0;
            for (int p = 0; p < NB / 2; ++p) {
                const v2f* wr = &WP[p * H];
                float a0 = 0.0f, a1 = 0.0f;
#pragma unroll
                for (int k = 0; k < H; ++k) {
                    v2f w = wr[k];
                    a0 = a0 + h[k] * w.x;
                    a1 = a1 + h[k] * w.y;
                }
                a0 = a0 + b_out[2 * p];
                a1 = a1 + b_out[2 * p + 1];
                if (a0 > bb2) { bb2 = a0; bj = 2 * p; }
                if (a1 > bb2) { bb2 = a1; bj = 2 * p + 1; }
            }
            bi = bj;
        } else if (kmx - ksec <= EPS2) {
            // exact 2-bin duel, first-index ties
            int lo  = kgb < ki2 ? kgb : ki2;
            int hi2 = kgb < ki2 ? ki2 : kgb;
            float El = 0.0f, Eh = 0.0f;
            {
                const float* wr = ws + (lo >> 1) * 32 + (lo & 1);
#pragma unroll
                for (int k = 0; k < H; ++k) El = El + h[k] * wr[2 * k];
                El = El + b_out[lo];
            }
            {
                const float* wr = ws + (hi2 >> 1) * 32 + (hi2 & 1);
#pragma unroll
                for (int k = 0; k < H; ++k) Eh = Eh + h[k] * wr[2 * k];
                Eh = Eh + b_out[hi2];
            }
            bi = (Eh > El) ? hi2 : lo;
        } else {
            bi = kgb;
        }
        o[d] = bi;

        // ---- h = h + embed[bi] : EXACT (global gather, cached) ----
        {
            const float4* e = reinterpret_cast<const float4*>(embed + bi * H);
#pragma unroll
            for (int q4 = 0; q4 < 4; ++q4) {
                float4 ev = e[q4];
                h[q4 * 4 + 0] = h[q4 * 4 + 0] + ev.x;
                h[q4 * 4 + 1] = h[q4 * 4 + 1] + ev.y;
                h[q4 * 4 + 2] = h[q4 * 4 + 2] + ev.z;
                h[q4 * 4 + 3] = h[q4 * 4 + 3] + ev.w;
            }
        }

        // ---- z = h @ W_mlp + b_mlp ; silu : EXACT no-FMA + np-exp ----
        float hn[H];
#pragma unroll
        for (int i = 0; i < H; ++i) {
            const float* wr = &WM[i * H];
            float acc = 0.0f;
#pragma unroll
            for (int k = 0; k < H; ++k) acc = acc + h[k] * wr[k];
            acc = acc + b_mlp[i];
            float e = np_expf(-acc);
            float s = 1.0f / (1.0f + e);
            hn[i] = acc * s;
        }
#pragma unroll
        for (int i = 0; i < H; ++i) h[i] = hn[i];
    }
}

extern "C" void kernel_launch(void* const* d_in, const int* in_sizes, int n_in,
                              void* d_out, int out_size, void* d_ws, size_t ws_size,
                              hipStream_t stream) {
    const float* x     = (const float*)d_in[0];
    const float* W_in  = (const float*)d_in[1];
    const float* b_in  = (const float*)d_in[2];
    const float* embed = (const float*)d_in[3];
    const float* W_mlp = (const float*)d_in[4];
    const float* b_mlp = (const float*)d_in[5];
    const float* W_out = (const float*)d_in[6];
    const float* b_out = (const float*)d_in[7];
    int* out  = (int*)d_out;
    float* ws = (float*)d_ws;          // needs (4096+256)*4 = 17.4 KB

    addrnet_prep_kernel<<<1, 256, 0, stream>>>(W_out, W_mlp, ws);

    dim3 grid(BATCH / BLOCK);          // 1024 blocks, 8192 waves
    dim3 block(BLOCK);
    addrnet_r21_kernel<<<grid, block, 0, stream>>>(x, W_in, b_in, embed,
                                                   b_mlp, b_out, W_out, ws, out);
}